// Round 11
// baseline (1056.463 us; speedup 1.0000x reference)
//
#include <hip/hip_runtime.h>

#define H 128
#define MB 64          // edges (or nodes) per tile
#define TPB 8          // tiles per block in edge_pipe
#define CAP 64         // bucket slots per node (deg ~ Poisson(32); overflow -> scan)
#define OVF_MAX 8192
#define LDA 264        // LDS row stride (elems) for the [64 x 256] concat tile (+8 pad)
#define LDB 136        // LDS row stride for [64 x 128] tiles (+8 pad)

typedef __attribute__((ext_vector_type(8))) short bf16x8;
typedef __attribute__((ext_vector_type(4))) short s16x4;
typedef __attribute__((ext_vector_type(4))) float f32x4;

__device__ __forceinline__ short f2bf(float f) {
    union { float f; unsigned u; } v; v.f = f;
    unsigned r = v.u + 0x7FFF + ((v.u >> 16) & 1);   // RTNE
    return (short)(r >> 16);
}
__device__ __forceinline__ float bf2f(short s) {
    union { unsigned u; float f; } v;
    v.u = ((unsigned)(unsigned short)s) << 16;
    return v.f;
}
__device__ __forceinline__ float bflo(unsigned u) {
    union { unsigned u; float f; } v; v.u = u << 16; return v.f;
}
__device__ __forceinline__ float bfhi(unsigned u) {
    union { unsigned u; float f; } v; v.u = u & 0xffff0000u; return v.f;
}

// ------------- fused prep: weights fp32->bf16T and node_rep fp32->bf16 -------
__global__ __launch_bounds__(256) void prep_all(
    const float* __restrict__ W1, const float* __restrict__ W2,
    const float* __restrict__ WL, const float* __restrict__ nr,
    short* __restrict__ W1T, short* __restrict__ W2T, short* __restrict__ WLT,
    short* __restrict__ nodeB, int total8)
{
    int t = blockIdx.x * 256 + threadIdx.x;
    if (t < 32768) {   // W1: [256,128] -> W1T [128][256]
        int n = t >> 8, k = t & 255;
        W1T[n * 256 + k] = f2bf(W1[k * 128 + n]);
    }
    if (t < 16384) {   // W2, W_lift: [128,128] -> [128][128]
        int n = t >> 7, k = t & 127;
        W2T[n * 128 + k] = f2bf(W2[k * 128 + n]);
        WLT[n * 128 + k] = f2bf(WL[k * 128 + n]);
    }
    if (t < total8) {
        const float4* p = (const float4*)nr + (size_t)t * 2;
        float4 a = p[0], b = p[1];
        bf16x8 v = { f2bf(a.x), f2bf(a.y), f2bf(a.z), f2bf(a.w),
                     f2bf(b.x), f2bf(b.y), f2bf(b.z), f2bf(b.w) };
        *(bf16x8*)(nodeB + (size_t)t * 8) = v;
    }
}

// ------------- single-pass bucket incidence build (dedicated; off the
// edge_pipe critical path -- R10 showed inline insertion costs 81 us there
// vs ~35 us here due to 64B-line RMW on scattered 4B stores) -------------
__global__ __launch_bounds__(256) void bucket_fill(
    const int* __restrict__ eidx, int* __restrict__ cnt,
    int* __restrict__ bucket, int* __restrict__ ovf_cnt,
    int* __restrict__ ovf, int E)
{
    int t = blockIdx.x * 256 + threadIdx.x;
    if (t < 2 * E) {
        int node = eidx[t];
        int e = (t < E) ? t : (t - E);
        int pos = atomicAdd(&cnt[node], 1);
        if (pos < CAP) {
            bucket[node * CAP + pos] = e;
        } else {
            int o = atomicAdd(ovf_cnt, 1);
            if (o < OVF_MAX) { ovf[o * 2] = node; ovf[o * 2 + 1] = e; }
        }
    }
}

// ------------- legacy CSR build (middle-ws fallback) -------------
__global__ __launch_bounds__(256) void count_deg(
    const int* __restrict__ eidx, int* __restrict__ deg, int twoE)
{
    int t = blockIdx.x * 256 + threadIdx.x;
    if (t < twoE) atomicAdd(&deg[eidx[t]], 1);
}

__global__ __launch_bounds__(1024) void scan_deg(
    const int* __restrict__ deg, int* __restrict__ row_start,
    int* __restrict__ cursor, int N)
{
    __shared__ int part[1024];
    const int t = threadIdx.x;
    const int chunk = (N + 1023) >> 10;
    const int b = t * chunk;
    const int e = (b + chunk < N) ? (b + chunk) : N;
    int s = 0;
    for (int j = b; j < e; ++j) s += deg[j];
    part[t] = s;
    __syncthreads();
    for (int off = 1; off < 1024; off <<= 1) {
        int v = part[t];
        int u = (t >= off) ? part[t - off] : 0;
        __syncthreads();
        part[t] = v + u;
        __syncthreads();
    }
    int run = (t == 0) ? 0 : part[t - 1];
    for (int j = b; j < e; ++j) {
        int d = deg[j];
        row_start[j] = run;
        cursor[j]    = run;
        run += d;
    }
    if (t == 1023) row_start[N] = part[1023];
}

__global__ __launch_bounds__(256) void fill_csr(
    const int* __restrict__ eidx, int* __restrict__ cursor,
    int* __restrict__ csr, int E)
{
    int t = blockIdx.x * 256 + threadIdx.x;
    if (t < 2 * E) {
        int node = eidx[t];
        int e = (t < E) ? t : (t - E);
        int pos = atomicAdd(&cursor[node], 1);
        csr[pos] = e;
    }
}

// ---------------- PATH A: pipelined fused edge kernel (R9 form) --------------
// 512 threads / 8 waves, each wave owns 16 output cols (VGPR ~80, below the
// 128 allocation step). Next tile's nodeB gathers + edge_rep stream prefetch
// into regs under GEMM1 -> stage phase is pure VALU+LDS-write. lift@WL folded
// into acc2; h (bf16) into the dead edge_rep half of sA; coalesced hbuf dump;
// GEMM2 h@WL; edge_out = relu(acc2 + e2*acc3). No bucket work here (R10
// lesson: scattered 4B stores on this critical path cost 64B-line RMWs).
__global__ __launch_bounds__(512) void edge_pipe(
    const short* __restrict__ nodeB, const float* __restrict__ edge_rep,
    const int* __restrict__ eidx,
    const short* __restrict__ W1T, const short* __restrict__ WLT,
    const float* __restrict__ eps2p,
    short* __restrict__ hbuf, float* __restrict__ edge_out,
    int E, int nTiles)
{
    __shared__ short sA[MB * LDA];   // cols [0,128)=lift, [128,256)=edge_rep then h

    const int tid  = threadIdx.x;
    const int row  = tid >> 3;          // 0..63 (8 threads per edge row)
    const int cs   = (tid & 7) << 4;    // 0,16,...,112
    const int wv   = tid >> 6;          // wave 0..7, owns cols [wv*16, wv*16+16)
    const int lane = tid & 63;
    const int m = lane & 15;            // A row / B col / D col
    const int q = lane >> 4;            // k-quad / D row group
    const float e2 = 1.f + eps2p[0];

    int t = blockIdx.x * TPB;
    if (t >= nTiles) return;
    const int tEnd = (t + TPB < nTiles) ? (t + TPB) : nTiles;

    // ---- prologue: gather tile t's node rows + edge_rep into registers ----
    bf16x8 pS[2], pD[2];
    float4 pE[4];
    bool pv;
    {
        int e = t * MB + row;
        pv = (e < E);
        if (pv) {
            int sIdx = eidx[e], dIdx = eidx[E + e];
            const bf16x8* sp = (const bf16x8*)(nodeB + (size_t)sIdx * H + cs);
            const bf16x8* dp = (const bf16x8*)(nodeB + (size_t)dIdx * H + cs);
            const float4* ep = (const float4*)(edge_rep + (size_t)e * H + cs);
            pS[0] = sp[0]; pS[1] = sp[1];
            pD[0] = dp[0]; pD[1] = dp[1];
            #pragma unroll
            for (int j = 0; j < 4; ++j) pE[j] = ep[j];
        }
    }

    for (; t < tEnd; ++t) {
        const int e0 = t * MB;

        // ---- stage: everything from prefetched regs (no HBM wait) ----
        {
            short* rowA = sA + row * LDA;
            if (pv) {
                #pragma unroll
                for (int j = 0; j < 2; ++j) {
                    bf16x8 lift;
                    #pragma unroll
                    for (int k = 0; k < 8; ++k)
                        lift[k] = f2bf(bf2f(pS[j][k]) + bf2f(pD[j][k]));
                    *(bf16x8*)&rowA[cs + 8 * j] = lift;
                }
                #pragma unroll
                for (int j = 0; j < 4; ++j) {
                    float4 c = pE[j];
                    s16x4 er = { f2bf(c.x), f2bf(c.y), f2bf(c.z), f2bf(c.w) };
                    *(s16x4*)&rowA[H + cs + 4 * j] = er;
                }
            } else {
                s16x4 z = {0, 0, 0, 0};
                #pragma unroll
                for (int j = 0; j < 4; ++j) {
                    int cc = cs + 4 * j;
                    *(s16x4*)&rowA[cc]     = z;
                    *(s16x4*)&rowA[H + cc] = z;
                }
            }
        }
        __syncthreads();

        // ---- issue next tile's prefetch (latency hidden under GEMM1) ----
        if (t + 1 < tEnd) {
            int e = (t + 1) * MB + row;
            pv = (e < E);
            if (pv) {
                int sIdx = eidx[e], dIdx = eidx[E + e];
                const bf16x8* sp = (const bf16x8*)(nodeB + (size_t)sIdx * H + cs);
                const bf16x8* dp = (const bf16x8*)(nodeB + (size_t)dIdx * H + cs);
                const float4* ep = (const float4*)(edge_rep + (size_t)e * H + cs);
                pS[0] = sp[0]; pS[1] = sp[1];
                pD[0] = dp[0]; pD[1] = dp[1];
                #pragma unroll
                for (int j = 0; j < 4; ++j) pE[j] = ep[j];
            }
        }

        // ---- GEMM1: acc = concat @ W1T;  acc2 = lift @ WLT (ks<4 fold) ----
        f32x4 zero = {0.f, 0.f, 0.f, 0.f};
        f32x4 acc[4], acc2[4];
        #pragma unroll
        for (int mt = 0; mt < 4; ++mt) { acc[mt] = zero; acc2[mt] = zero; }

        #pragma unroll
        for (int ks = 0; ks < 8; ++ks) {
            int k0 = ks * 32 + q * 8;
            bf16x8 aF[4];
            #pragma unroll
            for (int mt = 0; mt < 4; ++mt)
                aF[mt] = *(const bf16x8*)&sA[(mt * 16 + m) * LDA + k0];
            bf16x8 bF = *(const bf16x8*)&W1T[(wv * 16 + m) * 256 + k0];
            #pragma unroll
            for (int mt = 0; mt < 4; ++mt)
                acc[mt] = __builtin_amdgcn_mfma_f32_16x16x32_bf16(
                    aF[mt], bF, acc[mt], 0, 0, 0);
            if (ks < 4) {
                bf16x8 bL = *(const bf16x8*)&WLT[(wv * 16 + m) * 128 + k0];
                #pragma unroll
                for (int mt = 0; mt < 4; ++mt)
                    acc2[mt] = __builtin_amdgcn_mfma_f32_16x16x32_bf16(
                        aF[mt], bL, acc2[mt], 0, 0, 0);
            }
        }
        __syncthreads();   // all waves done reading sA

        // ---- epilogue: h = relu(acc) -> bf16 into the dead edge_rep half ----
        {
            int col = wv * 16 + m;
            #pragma unroll
            for (int mt = 0; mt < 4; ++mt) {
                #pragma unroll
                for (int i = 0; i < 4; ++i) {
                    int rr = (mt << 4) + (q << 2) + i;
                    float h = acc[mt][i];
                    h = h > 0.f ? h : 0.f;
                    sA[rr * LDA + H + col] = f2bf(h);
                }
            }
        }
        __syncthreads();

        // ---- coalesced hbuf dump (32B/thread from LDS) ----
        if (e0 + row < E) {
            bf16x8 h0 = *(const bf16x8*)&sA[row * LDA + H + cs];
            bf16x8 h1 = *(const bf16x8*)&sA[row * LDA + H + cs + 8];
            *(bf16x8*)&hbuf[(size_t)(e0 + row) * H + cs]     = h0;
            *(bf16x8*)&hbuf[(size_t)(e0 + row) * H + cs + 8] = h1;
        }

        // ---- GEMM2: acc3 = h @ WLT; edge_out = relu(acc2 + e2*acc3) ----
        f32x4 acc3[4];
        #pragma unroll
        for (int mt = 0; mt < 4; ++mt) acc3[mt] = zero;

        #pragma unroll
        for (int ks = 0; ks < 4; ++ks) {
            int k0 = ks * 32 + q * 8;
            bf16x8 aF[4];
            #pragma unroll
            for (int mt = 0; mt < 4; ++mt)
                aF[mt] = *(const bf16x8*)&sA[(mt * 16 + m) * LDA + H + k0];
            bf16x8 bF = *(const bf16x8*)&WLT[(wv * 16 + m) * 128 + k0];
            #pragma unroll
            for (int mt = 0; mt < 4; ++mt)
                acc3[mt] = __builtin_amdgcn_mfma_f32_16x16x32_bf16(
                    aF[mt], bF, acc3[mt], 0, 0, 0);
        }

        {
            int col = wv * 16 + m;
            #pragma unroll
            for (int mt = 0; mt < 4; ++mt) {
                #pragma unroll
                for (int i = 0; i < 4; ++i) {
                    int rr = (mt << 4) + (q << 2) + i;
                    if (e0 + rr < E) {
                        float v = acc2[mt][i] + e2 * acc3[mt][i];
                        edge_out[(size_t)(e0 + rr) * H + col] = v > 0.f ? v : 0.f;
                    }
                }
            }
        }
        __syncthreads();   // GEMM2 + dump reads done before next stage overwrites sA
    }
}

// ---------------- fused node aggregation + GEMM ----------------
// 512 threads / 8 waves per block; block owns 64 nodes. Phase 1: per round a
// wave aggregates one node: the bucket row is loaded ONCE coalesced (one int
// per lane) and edge indices are distributed by __shfl (VALU) -- no per-iter
// bucket load in the gather chain; 4 independent 16B gathers in flight/lane.
// Adds e1*node_rep, writes bf16 row into LDS. Phase 2: 64x128 GEMM with W2T.
__global__ __launch_bounds__(512) void node_fused(
    const uint4* __restrict__ hb, const int* __restrict__ bucket,
    const int* __restrict__ cnt, const float* __restrict__ node_rep,
    const short* __restrict__ W2T,
    const int* __restrict__ ovf_cnt, const int* __restrict__ ovf,
    const float* __restrict__ eps1p, float* __restrict__ node_out, int N)
{
    __shared__ short sA[MB * LDB];

    const int tid  = threadIdx.x;
    const int wv   = tid >> 6;
    const int lane = tid & 63;
    const int qt = lane >> 4, li = lane & 15;   // lane covers cols li*8..li*8+7
    const int r0 = blockIdx.x * MB;
    const float e1 = 1.f + eps1p[0];

    int m_ovf = *ovf_cnt;
    if (m_ovf > OVF_MAX) m_ovf = OVF_MAX;

    // ---- phase 1: aggregate + bias, write bf16 rows into LDS ----
    for (int rnd = 0; rnd < 8; ++rnd) {
        int n = r0 + rnd * 8 + wv;
        if (n < N) {
            int d = cnt[n];
            if (d > CAP) d = CAP;
            // coalesced bucket-row preload: lane holds slot `lane`'s edge idx
            int myIdx = (lane < d) ? bucket[n * CAP + lane] : 0;
            float a0 = 0.f, a1 = 0.f, a2 = 0.f, a3 = 0.f;
            float a4 = 0.f, a5 = 0.f, a6 = 0.f, a7 = 0.f;

            int base = 0;
            for (; base + 16 <= d; base += 16) {
                int eA = __shfl(myIdx, base + qt);
                int eB = __shfl(myIdx, base + qt + 4);
                int eC = __shfl(myIdx, base + qt + 8);
                int eD = __shfl(myIdx, base + qt + 12);
                uint4 vA = hb[(size_t)eA * 16 + li];
                uint4 vB = hb[(size_t)eB * 16 + li];
                uint4 vC = hb[(size_t)eC * 16 + li];
                uint4 vD = hb[(size_t)eD * 16 + li];
                a0 += (bflo(vA.x) + bflo(vB.x)) + (bflo(vC.x) + bflo(vD.x));
                a1 += (bfhi(vA.x) + bfhi(vB.x)) + (bfhi(vC.x) + bfhi(vD.x));
                a2 += (bflo(vA.y) + bflo(vB.y)) + (bflo(vC.y) + bflo(vD.y));
                a3 += (bfhi(vA.y) + bfhi(vB.y)) + (bfhi(vC.y) + bfhi(vD.y));
                a4 += (bflo(vA.z) + bflo(vB.z)) + (bflo(vC.z) + bflo(vD.z));
                a5 += (bfhi(vA.z) + bfhi(vB.z)) + (bfhi(vC.z) + bfhi(vD.z));
                a6 += (bflo(vA.w) + bflo(vB.w)) + (bflo(vC.w) + bflo(vD.w));
                a7 += (bfhi(vA.w) + bfhi(vB.w)) + (bfhi(vC.w) + bfhi(vD.w));
            }
            for (; base + 4 <= d; base += 4) {
                int eA = __shfl(myIdx, base + qt);
                uint4 vA = hb[(size_t)eA * 16 + li];
                a0 += bflo(vA.x);  a1 += bfhi(vA.x);
                a2 += bflo(vA.y);  a3 += bfhi(vA.y);
                a4 += bflo(vA.z);  a5 += bfhi(vA.z);
                a6 += bflo(vA.w);  a7 += bfhi(vA.w);
            }
            int rem = d - base;     // 0..3
            {
                int eA = __shfl(myIdx, base + (qt < rem ? qt : 0));
                if (qt < rem) {
                    uint4 vA = hb[(size_t)eA * 16 + li];
                    a0 += bflo(vA.x);  a1 += bfhi(vA.x);
                    a2 += bflo(vA.y);  a3 += bfhi(vA.y);
                    a4 += bflo(vA.z);  a5 += bfhi(vA.z);
                    a6 += bflo(vA.w);  a7 += bfhi(vA.w);
                }
            }
            // rare overflow entries (m_ovf ~ 0 in practice)
            for (int o = qt; o < m_ovf; o += 4) {
                if (ovf[o * 2] == n) {
                    uint4 vA = hb[(size_t)ovf[o * 2 + 1] * 16 + li];
                    a0 += bflo(vA.x);  a1 += bfhi(vA.x);
                    a2 += bflo(vA.y);  a3 += bfhi(vA.y);
                    a4 += bflo(vA.z);  a5 += bfhi(vA.z);
                    a6 += bflo(vA.w);  a7 += bfhi(vA.w);
                }
            }
            a0 += __shfl_xor(a0, 16); a1 += __shfl_xor(a1, 16);
            a2 += __shfl_xor(a2, 16); a3 += __shfl_xor(a3, 16);
            a4 += __shfl_xor(a4, 16); a5 += __shfl_xor(a5, 16);
            a6 += __shfl_xor(a6, 16); a7 += __shfl_xor(a7, 16);
            a0 += __shfl_xor(a0, 32); a1 += __shfl_xor(a1, 32);
            a2 += __shfl_xor(a2, 32); a3 += __shfl_xor(a3, 32);
            a4 += __shfl_xor(a4, 32); a5 += __shfl_xor(a5, 32);
            a6 += __shfl_xor(a6, 32); a7 += __shfl_xor(a7, 32);
            if (qt == 0) {
                const float4* np = (const float4*)(node_rep + (size_t)n * H + li * 8);
                float4 n0 = np[0], n1 = np[1];
                bf16x8 v = { f2bf(e1 * n0.x + a0), f2bf(e1 * n0.y + a1),
                             f2bf(e1 * n0.z + a2), f2bf(e1 * n0.w + a3),
                             f2bf(e1 * n1.x + a4), f2bf(e1 * n1.y + a5),
                             f2bf(e1 * n1.z + a6), f2bf(e1 * n1.w + a7) };
                *(bf16x8*)&sA[(rnd * 8 + wv) * LDB + li * 8] = v;
            }
        } else if (qt == 0) {
            bf16x8 z = {0,0,0,0,0,0,0,0};
            *(bf16x8*)&sA[(rnd * 8 + wv) * LDB + li * 8] = z;
        }
    }
    __syncthreads();

    // ---- phase 2: node_out = relu(sA @ W2T) ----
    const int m = lane & 15;
    const int q = lane >> 4;
    f32x4 zero = {0.f, 0.f, 0.f, 0.f};
    f32x4 acc[4];
    #pragma unroll
    for (int mt = 0; mt < 4; ++mt) acc[mt] = zero;

    #pragma unroll
    for (int ks = 0; ks < 4; ++ks) {
        int k0 = ks * 32 + q * 8;
        bf16x8 aF[4];
        #pragma unroll
        for (int mt = 0; mt < 4; ++mt)
            aF[mt] = *(const bf16x8*)&sA[(mt * 16 + m) * LDB + k0];
        bf16x8 bF = *(const bf16x8*)&W2T[(wv * 16 + m) * 128 + k0];
        #pragma unroll
        for (int mt = 0; mt < 4; ++mt)
            acc[mt] = __builtin_amdgcn_mfma_f32_16x16x32_bf16(
                aF[mt], bF, acc[mt], 0, 0, 0);
    }

    {
        int col = wv * 16 + m;
        #pragma unroll
        for (int mt = 0; mt < 4; ++mt) {
            #pragma unroll
            for (int i = 0; i < 4; ++i) {
                int rr = (mt << 4) + (q << 2) + i;
                if (r0 + rr < N) {
                    float v = acc[mt][i];
                    node_out[(size_t)(r0 + rr) * H + col] = v > 0.f ? v : 0.f;
                }
            }
        }
    }
}

// ---------------- node aggregation (CSR layout, middle-ws fallback) ----------
__global__ __launch_bounds__(256) void node_aggr_csr(
    const uint4* __restrict__ hb, const int* __restrict__ csr,
    const int* __restrict__ row_start, float* __restrict__ lvl, int N)
{
    const int wid = threadIdx.x >> 6, lane = threadIdx.x & 63;
    const int n = blockIdx.x * 4 + wid;
    if (n >= N) return;
    const int qt = lane >> 4, li = lane & 15;
    const int beg = row_start[n], end = row_start[n + 1];
    float a0 = 0.f, a1 = 0.f, a2 = 0.f, a3 = 0.f;
    float a4 = 0.f, a5 = 0.f, a6 = 0.f, a7 = 0.f;

    int i = beg;
    for (; i + 8 <= end; i += 8) {
        int eA = csr[i + qt], eB = csr[i + 4 + qt];
        uint4 vA = hb[(size_t)eA * 16 + li];
        uint4 vB = hb[(size_t)eB * 16 + li];
        a0 += bflo(vA.x) + bflo(vB.x);  a1 += bfhi(vA.x) + bfhi(vB.x);
        a2 += bflo(vA.y) + bflo(vB.y);  a3 += bfhi(vA.y) + bfhi(vB.y);
        a4 += bflo(vA.z) + bflo(vB.z);  a5 += bfhi(vA.z) + bfhi(vB.z);
        a6 += bflo(vA.w) + bflo(vB.w);  a7 += bfhi(vA.w) + bfhi(vB.w);
    }
    if (i + 4 <= end) {
        int eA = csr[i + qt];
        uint4 vA = hb[(size_t)eA * 16 + li];
        a0 += bflo(vA.x);  a1 += bfhi(vA.x);
        a2 += bflo(vA.y);  a3 += bfhi(vA.y);
        a4 += bflo(vA.z);  a5 += bfhi(vA.z);
        a6 += bflo(vA.w);  a7 += bfhi(vA.w);
        i += 4;
    }
    int rem = end - i;
    if (qt < rem) {
        int eA = csr[i + qt];
        uint4 vA = hb[(size_t)eA * 16 + li];
        a0 += bflo(vA.x);  a1 += bfhi(vA.x);
        a2 += bflo(vA.y);  a3 += bfhi(vA.y);
        a4 += bflo(vA.z);  a5 += bfhi(vA.z);
        a6 += bflo(vA.w);  a7 += bfhi(vA.w);
    }
    a0 += __shfl_xor(a0, 16); a1 += __shfl_xor(a1, 16);
    a2 += __shfl_xor(a2, 16); a3 += __shfl_xor(a3, 16);
    a4 += __shfl_xor(a4, 16); a5 += __shfl_xor(a5, 16);
    a6 += __shfl_xor(a6, 16); a7 += __shfl_xor(a7, 16);
    a0 += __shfl_xor(a0, 32); a1 += __shfl_xor(a1, 32);
    a2 += __shfl_xor(a2, 32); a3 += __shfl_xor(a3, 32);
    a4 += __shfl_xor(a4, 32); a5 += __shfl_xor(a5, 32);
    a6 += __shfl_xor(a6, 32); a7 += __shfl_xor(a7, 32);
    if (qt == 0) {
        float* dst = lvl + (size_t)n * H + li * 8;
        float4 o0; o0.x = a0; o0.y = a1; o0.z = a2; o0.w = a3;
        float4 o1; o1.x = a4; o1.y = a5; o1.z = a6; o1.w = a7;
        *(float4*)dst = o0;
        *(float4*)(dst + 4) = o1;
    }
}

// ---------------- LEGACY edge kernel (atomic scatter) -- tiny-ws fallback ----
__global__ __launch_bounds__(256) void edge_kernel(
    const float* __restrict__ node_rep, const float* __restrict__ edge_rep,
    const int* __restrict__ eidx,
    const short* __restrict__ W1T, const short* __restrict__ WLT,
    const float* __restrict__ eps2p,
    float* __restrict__ lvl, float* __restrict__ edge_out, int E)
{
    __shared__ short sA[MB * LDA];
    __shared__ short sB[MB * LDB];
    __shared__ int sSrc[MB], sDst[MB];

    const int tid = threadIdx.x;
    const int e0  = blockIdx.x * MB;
    const float e2 = 1.f + eps2p[0];
    {
        int row  = tid >> 2;
        int cseg = (tid & 3) << 5;
        int e = e0 + row;
        int sIdx = 0, dIdx = 0;
        bool ev = (e < E);
        if (ev) { sIdx = eidx[e]; dIdx = eidx[E + e]; }
        if ((tid & 3) == 0) { sSrc[row] = sIdx; sDst[row] = dIdx; }
        short* rowA = sA + row * LDA;
        if (ev) {
            const float4* sp = (const float4*)(node_rep + (size_t)sIdx * H + cseg);
            const float4* dp = (const float4*)(node_rep + (size_t)dIdx * H + cseg);
            const float4* ep = (const float4*)(edge_rep + (size_t)e * H + cseg);
            #pragma unroll
            for (int j = 0; j < 8; ++j) {
                float4 a = sp[j], b = dp[j], c = ep[j];
                int cc = cseg + 4 * j;
                s16x4 lift = { f2bf(a.x + b.x), f2bf(a.y + b.y),
                               f2bf(a.z + b.z), f2bf(a.w + b.w) };
                s16x4 er   = { f2bf(c.x), f2bf(c.y), f2bf(c.z), f2bf(c.w) };
                *(s16x4*)&rowA[cc]      = lift;
                *(s16x4*)&rowA[H + cc]  = er;
            }
        } else {
            s16x4 z = {0, 0, 0, 0};
            #pragma unroll
            for (int j = 0; j < 8; ++j) {
                int cc = cseg + 4 * j;
                *(s16x4*)&rowA[cc]     = z;
                *(s16x4*)&rowA[H + cc] = z;
            }
        }
    }
    __syncthreads();

    const int wave = tid >> 6;
    const int lane = tid & 63;
    const int m = lane & 15;
    const int q = lane >> 4;

    f32x4 zero = {0.f, 0.f, 0.f, 0.f};
    f32x4 acc[4][2];
    #pragma unroll
    for (int mt = 0; mt < 4; ++mt)
        #pragma unroll
        for (int nt = 0; nt < 2; ++nt) acc[mt][nt] = zero;

    #pragma unroll
    for (int ks = 0; ks < 8; ++ks) {
        int k0 = ks * 32 + q * 8;
        bf16x8 aF[4];
        #pragma unroll
        for (int mt = 0; mt < 4; ++mt)
            aF[mt] = *(const bf16x8*)&sA[(mt * 16 + m) * LDA + k0];
        bf16x8 bF[2];
        #pragma unroll
        for (int nt = 0; nt < 2; ++nt) {
            int n = (wave << 5) + (nt << 4) + m;
            bF[nt] = *(const bf16x8*)&W1T[n * 256 + k0];
        }
        #pragma unroll
        for (int mt = 0; mt < 4; ++mt)
            #pragma unroll
            for (int nt = 0; nt < 2; ++nt)
                acc[mt][nt] = __builtin_amdgcn_mfma_f32_16x16x32_bf16(
                    aF[mt], bF[nt], acc[mt][nt], 0, 0, 0);
    }

    #pragma unroll
    for (int mt = 0; mt < 4; ++mt) {
        #pragma unroll
        for (int nt = 0; nt < 2; ++nt) {
            int col = (wave << 5) + (nt << 4) + m;
            #pragma unroll
            for (int i = 0; i < 4; ++i) {
                int rr = (mt << 4) + (q << 2) + i;
                if (e0 + rr < E) {
                    float h = acc[mt][nt][i];
                    h = h > 0.f ? h : 0.f;
                    int sn = sSrc[rr], dn = sDst[rr];
                    atomicAdd(lvl + (size_t)sn * H + col, h);
                    atomicAdd(lvl + (size_t)dn * H + col, h);
                    float b2 = e2 * h + bf2f(sA[rr * LDA + col]);
                    sB[rr * LDB + col] = f2bf(b2);
                }
            }
        }
    }
    __syncthreads();

    f32x4 acc2[4][2];
    #pragma unroll
    for (int mt = 0; mt < 4; ++mt)
        #pragma unroll
        for (int nt = 0; nt < 2; ++nt) acc2[mt][nt] = zero;

    #pragma unroll
    for (int ks = 0; ks < 4; ++ks) {
        int k0 = ks * 32 + q * 8;
        bf16x8 aF[4];
        #pragma unroll
        for (int mt = 0; mt < 4; ++mt)
            aF[mt] = *(const bf16x8*)&sB[(mt * 16 + m) * LDB + k0];
        bf16x8 bF[2];
        #pragma unroll
        for (int nt = 0; nt < 2; ++nt) {
            int n = (wave << 5) + (nt << 4) + m;
            bF[nt] = *(const bf16x8*)&WLT[n * 128 + k0];
        }
        #pragma unroll
        for (int mt = 0; mt < 4; ++mt)
            #pragma unroll
            for (int nt = 0; nt < 2; ++nt)
                acc2[mt][nt] = __builtin_amdgcn_mfma_f32_16x16x32_bf16(
                    aF[mt], bF[nt], acc2[mt][nt], 0, 0, 0);
    }

    #pragma unroll
    for (int mt = 0; mt < 4; ++mt) {
        #pragma unroll
        for (int nt = 0; nt < 2; ++nt) {
            int col = (wave << 5) + (nt << 4) + m;
            #pragma unroll
            for (int i = 0; i < 4; ++i) {
                int rr = (mt << 4) + (q << 2) + i;
                if (e0 + rr < E) {
                    float v = acc2[mt][nt][i];
                    edge_out[(size_t)(e0 + rr) * H + col] = v > 0.f ? v : 0.f;
                }
            }
        }
    }
}

// ---------------- node kernel (fallback paths) ----------------
__global__ __launch_bounds__(256) void node_kernel(
    const float* __restrict__ node_rep, const float* __restrict__ lvl,
    const short* __restrict__ W2T, const float* __restrict__ eps1p,
    float* __restrict__ node_out, int N)
{
    __shared__ short sA[MB * LDB];

    const int tid = threadIdx.x;
    const int r0  = blockIdx.x * MB;
    const float e1 = 1.f + eps1p[0];

    {
        int row  = tid >> 2;
        int cseg = (tid & 3) << 5;
        int r = r0 + row;
        short* rowA = sA + row * LDB;
        if (r < N) {
            const float4* np = (const float4*)(node_rep + (size_t)r * H + cseg);
            const float4* lp = (const float4*)(lvl + (size_t)r * H + cseg);
            #pragma unroll
            for (int j = 0; j < 8; ++j) {
                float4 a = np[j], b = lp[j];
                int cc = cseg + 4 * j;
                s16x4 v = { f2bf(e1 * a.x + b.x), f2bf(e1 * a.y + b.y),
                            f2bf(e1 * a.z + b.z), f2bf(e1 * a.w + b.w) };
                *(s16x4*)&rowA[cc] = v;
            }
        } else {
            s16x4 z = {0, 0, 0, 0};
            #pragma unroll
            for (int j = 0; j < 8; ++j) *(s16x4*)&rowA[cseg + 4 * j] = z;
        }
    }
    __syncthreads();

    const int wave = tid >> 6;
    const int lane = tid & 63;
    const int m = lane & 15;
    const int q = lane >> 4;

    f32x4 zero = {0.f, 0.f, 0.f, 0.f};
    f32x4 acc[4][2];
    #pragma unroll
    for (int mt = 0; mt < 4; ++mt)
        #pragma unroll
        for (int nt = 0; nt < 2; ++nt) acc[mt][nt] = zero;

    #pragma unroll
    for (int ks = 0; ks < 4; ++ks) {
        int k0 = ks * 32 + q * 8;
        bf16x8 aF[4];
        #pragma unroll
        for (int mt = 0; mt < 4; ++mt)
            aF[mt] = *(const bf16x8*)&sA[(mt * 16 + m) * LDB + k0];
        bf16x8 bF[2];
        #pragma unroll
        for (int nt = 0; nt < 2; ++nt) {
            int n = (wave << 5) + (nt << 4) + m;
            bF[nt] = *(const bf16x8*)&W2T[n * 128 + k0];
        }
        #pragma unroll
        for (int mt = 0; mt < 4; ++mt)
            #pragma unroll
            for (int nt = 0; nt < 2; ++nt)
                acc[mt][nt] = __builtin_amdgcn_mfma_f32_16x16x32_bf16(
                    aF[mt], bF[nt], acc[mt][nt], 0, 0, 0);
    }

    #pragma unroll
    for (int mt = 0; mt < 4; ++mt) {
        #pragma unroll
        for (int nt = 0; nt < 2; ++nt) {
            int col = (wave << 5) + (nt << 4) + m;
            #pragma unroll
            for (int i = 0; i < 4; ++i) {
                int rr = (mt << 4) + (q << 2) + i;
                if (r0 + rr < N) {
                    float v = acc[mt][nt][i];
                    node_out[(size_t)(r0 + rr) * H + col] = v > 0.f ? v : 0.f;
                }
            }
        }
    }
}

static inline size_t algn(size_t x) { return (x + 255) & ~(size_t)255; }

extern "C" void kernel_launch(void* const* d_in, const int* in_sizes, int n_in,
                              void* d_out, int out_size, void* d_ws, size_t ws_size,
                              hipStream_t stream) {
    const float* node_rep = (const float*)d_in[0];
    const float* edge_rep = (const float*)d_in[1];
    const int*   eidx     = (const int*)d_in[2];
    const float* W1       = (const float*)d_in[3];
    const float* W2       = (const float*)d_in[4];
    const float* WL       = (const float*)d_in[5];
    const float* eps1     = (const float*)d_in[6];
    const float* eps2     = (const float*)d_in[7];

    const int N = in_sizes[0] / H;     // 50000
    const int E = in_sizes[1] / H;     // 800000

    float* node_out = (float*)d_out;
    float* edge_out = (float*)d_out + (size_t)N * H;
    float* lvl = node_out;             // fallback paths only (in-place safe)

    char* ws = (char*)d_ws;
    short* W1T = (short*)ws;                       // 64 KB
    short* W2T = (short*)(ws + 65536);             // 32 KB
    short* WLT = (short*)(ws + 65536 + 32768);     // 32 KB
    size_t off0 = 131072;

    // shared buffers (both fast paths)
    short* hbuf  = (short*)(ws + off0);
    size_t offh  = off0 + algn((size_t)E * H * sizeof(short));
    short* nodeB = (short*)(ws + offh);
    size_t offn  = offh + algn((size_t)N * H * sizeof(short));

    // bucket-path region
    size_t ob = offn;
    int* cnt     = (int*)(ws + ob); ob += algn((size_t)N * 4);
    int* ovf_cnt = (int*)(ws + ob); ob += 256;
    int* ovf     = (int*)(ws + ob); ob += algn((size_t)OVF_MAX * 2 * 4);
    int* bucket  = (int*)(ws + ob); ob += algn((size_t)N * CAP * 4);
    const size_t need_bucket = ob;

    // csr-path region (overlaps bucket region; only one path runs)
    size_t oc = offn;
    int* deg       = (int*)(ws + oc); oc += algn((size_t)N * 4);
    int* row_start = (int*)(ws + oc); oc += algn((size_t)(N + 1) * 4);
    int* cursor    = (int*)(ws + oc); oc += algn((size_t)N * 4);
    int* csr       = (int*)(ws + oc); oc += algn((size_t)2 * E * 4);
    const size_t need_csr = oc;

    const int twoE = 2 * E;
    const int egrid = (E + MB - 1) / MB;
    const int ngrid = (N + MB - 1) / MB;
    const int total8 = (N * H) / 8;
    const int nTiles = (E + MB - 1) / MB;
    const int pgrid = (nTiles + TPB - 1) / TPB;

    if (ws_size >= need_bucket) {
        prep_all<<<(total8 + 255) / 256, 256, 0, stream>>>(
            W1, W2, WL, node_rep, W1T, W2T, WLT, nodeB, total8);
        hipMemsetAsync(cnt, 0, (size_t)N * 4, stream);
        hipMemsetAsync(ovf_cnt, 0, 4, stream);
        bucket_fill<<<(twoE + 255) / 256, 256, 0, stream>>>(
            eidx, cnt, bucket, ovf_cnt, ovf, E);
        edge_pipe<<<pgrid, 512, 0, stream>>>(
            nodeB, edge_rep, eidx, W1T, WLT, eps2, hbuf, edge_out, E, nTiles);
        node_fused<<<(N + MB - 1) / MB, 512, 0, stream>>>(
            (const uint4*)hbuf, bucket, cnt, node_rep, W2T,
            ovf_cnt, ovf, eps1, node_out, N);
    } else if (ws_size >= need_csr) {
        prep_all<<<(total8 + 255) / 256, 256, 0, stream>>>(
            W1, W2, WL, node_rep, W1T, W2T, WLT, nodeB, total8);
        hipMemsetAsync(deg, 0, (size_t)N * 4, stream);
        count_deg<<<(twoE + 255) / 256, 256, 0, stream>>>(eidx, deg, twoE);
        scan_deg<<<1, 1024, 0, stream>>>(deg, row_start, cursor, N);
        fill_csr<<<(twoE + 255) / 256, 256, 0, stream>>>(eidx, cursor, csr, E);
        edge_pipe<<<pgrid, 512, 0, stream>>>(
            nodeB, edge_rep, eidx, W1T, WLT, eps2, hbuf, edge_out, E, nTiles);
        node_aggr_csr<<<(N + 3) / 4, 256, 0, stream>>>(
            (const uint4*)hbuf, csr, row_start, lvl, N);
        node_kernel<<<ngrid, 256, 0, stream>>>(
            node_rep, lvl, W2T, eps1, node_out, N);
    } else {
        // LEGACY: atomic scatter (weights only need 128 KB)
        prep_all<<<(total8 + 255) / 256, 256, 0, stream>>>(
            W1, W2, WL, node_rep, W1T, W2T, WLT, (short*)W1T, 0);
        hipMemsetAsync(lvl, 0, (size_t)N * H * sizeof(float), stream);
        edge_kernel<<<egrid, 256, 0, stream>>>(
            node_rep, edge_rep, eidx, W1T, WLT, eps2, lvl, edge_out, E);
        node_kernel<<<ngrid, 256, 0, stream>>>(
            node_rep, lvl, W2T, eps1, node_out, N);
    }
}

// Round 12
// 988.611 us; speedup vs baseline: 1.0686x; 1.0686x over previous
//
#include <hip/hip_runtime.h>

#define H 128
#define MB 64          // edges (or nodes) per tile
#define TPB 8          // tiles per block in edge_pipe
#define BKG 1024       // bucket-builder blocks appended to edge_pipe's grid
#define CAP 64         // bucket slots per node (deg ~ Poisson(32); overflow -> scan)
#define OVF_MAX 8192
#define LDA 264        // LDS row stride (elems) for the [64 x 256] concat tile (+8 pad)
#define LDB 136        // LDS row stride for [64 x 128] tiles (+8 pad)

typedef __attribute__((ext_vector_type(8))) short bf16x8;
typedef __attribute__((ext_vector_type(4))) short s16x4;
typedef __attribute__((ext_vector_type(4))) float f32x4;

__device__ __forceinline__ short f2bf(float f) {
    union { float f; unsigned u; } v; v.f = f;
    unsigned r = v.u + 0x7FFF + ((v.u >> 16) & 1);   // RTNE
    return (short)(r >> 16);
}
__device__ __forceinline__ float bf2f(short s) {
    union { unsigned u; float f; } v;
    v.u = ((unsigned)(unsigned short)s) << 16;
    return v.f;
}
__device__ __forceinline__ float bflo(unsigned u) {
    union { unsigned u; float f; } v; v.u = u << 16; return v.f;
}
__device__ __forceinline__ float bfhi(unsigned u) {
    union { unsigned u; float f; } v; v.u = u & 0xffff0000u; return v.f;
}

// ------------- fused prep: weights fp32->bf16T and node_rep fp32->bf16 -------
__global__ __launch_bounds__(256) void prep_all(
    const float* __restrict__ W1, const float* __restrict__ W2,
    const float* __restrict__ WL, const float* __restrict__ nr,
    short* __restrict__ W1T, short* __restrict__ W2T, short* __restrict__ WLT,
    short* __restrict__ nodeB, int total8)
{
    int t = blockIdx.x * 256 + threadIdx.x;
    if (t < 32768) {   // W1: [256,128] -> W1T [128][256]
        int n = t >> 8, k = t & 255;
        W1T[n * 256 + k] = f2bf(W1[k * 128 + n]);
    }
    if (t < 16384) {   // W2, W_lift: [128,128] -> [128][128]
        int n = t >> 7, k = t & 127;
        W2T[n * 128 + k] = f2bf(W2[k * 128 + n]);
        WLT[n * 128 + k] = f2bf(WL[k * 128 + n]);
    }
    if (t < total8) {
        const float4* p = (const float4*)nr + (size_t)t * 2;
        float4 a = p[0], b = p[1];
        bf16x8 v = { f2bf(a.x), f2bf(a.y), f2bf(a.z), f2bf(a.w),
                     f2bf(b.x), f2bf(b.y), f2bf(b.z), f2bf(b.w) };
        *(bf16x8*)(nodeB + (size_t)t * 8) = v;
    }
}

// ------------- legacy CSR build (middle-ws fallback) -------------
__global__ __launch_bounds__(256) void count_deg(
    const int* __restrict__ eidx, int* __restrict__ deg, int twoE)
{
    int t = blockIdx.x * 256 + threadIdx.x;
    if (t < twoE) atomicAdd(&deg[eidx[t]], 1);
}

__global__ __launch_bounds__(1024) void scan_deg(
    const int* __restrict__ deg, int* __restrict__ row_start,
    int* __restrict__ cursor, int N)
{
    __shared__ int part[1024];
    const int t = threadIdx.x;
    const int chunk = (N + 1023) >> 10;
    const int b = t * chunk;
    const int e = (b + chunk < N) ? (b + chunk) : N;
    int s = 0;
    for (int j = b; j < e; ++j) s += deg[j];
    part[t] = s;
    __syncthreads();
    for (int off = 1; off < 1024; off <<= 1) {
        int v = part[t];
        int u = (t >= off) ? part[t - off] : 0;
        __syncthreads();
        part[t] = v + u;
        __syncthreads();
    }
    int run = (t == 0) ? 0 : part[t - 1];
    for (int j = b; j < e; ++j) {
        int d = deg[j];
        row_start[j] = run;
        cursor[j]    = run;
        run += d;
    }
    if (t == 1023) row_start[N] = part[1023];
}

__global__ __launch_bounds__(256) void fill_csr(
    const int* __restrict__ eidx, int* __restrict__ cursor,
    int* __restrict__ csr, int E)
{
    int t = blockIdx.x * 256 + threadIdx.x;
    if (t < 2 * E) {
        int node = eidx[t];
        int e = (t < E) ? t : (t - E);
        int pos = atomicAdd(&cursor[node], 1);
        csr[pos] = e;
    }
}

// ---------------- PATH A: pipelined fused edge kernel + concurrent bucket ----
// Blocks [0, pgrid): edge tiles -- 512 threads / 8 waves, each wave owns 16
// output cols (VGPR ~80). Next tile's nodeB gathers + edge_rep stream prefetch
// into regs under GEMM1. lift@WL folded into acc2; h (bf16) into the dead
// edge_rep half of sA; coalesced hbuf dump; GEMM2 h@WL.
// Blocks [pgrid, pgrid+BKG): bucket builders -- grid-stride over 2E doing the
// incidence-bucket scatter CONCURRENTLY with the edge tiles (R10/R11 lesson:
// as a dedicated pass this scatter costs ~130us serialized; on the per-tile
// critical path it costs ~81us; as concurrent blocks it hides in edge_pipe's
// idle memory pipes). Kernel boundary before node_fused guarantees completion.
__global__ __launch_bounds__(512) void edge_pipe(
    const short* __restrict__ nodeB, const float* __restrict__ edge_rep,
    const int* __restrict__ eidx,
    const short* __restrict__ W1T, const short* __restrict__ WLT,
    const float* __restrict__ eps2p,
    short* __restrict__ hbuf, float* __restrict__ edge_out,
    int* __restrict__ cnt, int* __restrict__ bucket,
    int* __restrict__ ovf_cnt, int* __restrict__ ovf,
    int E, int nTiles, int pgrid)
{
    __shared__ short sA[MB * LDA];   // cols [0,128)=lift, [128,256)=edge_rep then h

    const int tid  = threadIdx.x;

    // ---- bucket-builder blocks ----
    if (blockIdx.x >= pgrid) {
        if (cnt == nullptr) return;
        int bb = blockIdx.x - pgrid;
        int stride = BKG * 512;
        for (int t = bb * 512 + tid; t < 2 * E; t += stride) {
            int node = eidx[t];
            int e = (t < E) ? t : (t - E);
            int pos = atomicAdd(&cnt[node], 1);
            if (pos < CAP) {
                bucket[node * CAP + pos] = e;
            } else {
                int o = atomicAdd(ovf_cnt, 1);
                if (o < OVF_MAX) { ovf[o * 2] = node; ovf[o * 2 + 1] = e; }
            }
        }
        return;
    }

    const int row  = tid >> 3;          // 0..63 (8 threads per edge row)
    const int cs   = (tid & 7) << 4;    // 0,16,...,112
    const int wv   = tid >> 6;          // wave 0..7, owns cols [wv*16, wv*16+16)
    const int lane = tid & 63;
    const int m = lane & 15;            // A row / B col / D col
    const int q = lane >> 4;            // k-quad / D row group
    const float e2 = 1.f + eps2p[0];

    int t = blockIdx.x * TPB;
    if (t >= nTiles) return;
    const int tEnd = (t + TPB < nTiles) ? (t + TPB) : nTiles;

    // ---- prologue: gather tile t's node rows + edge_rep into registers ----
    bf16x8 pS[2], pD[2];
    float4 pE[4];
    bool pv;
    {
        int e = t * MB + row;
        pv = (e < E);
        if (pv) {
            int sIdx = eidx[e], dIdx = eidx[E + e];
            const bf16x8* sp = (const bf16x8*)(nodeB + (size_t)sIdx * H + cs);
            const bf16x8* dp = (const bf16x8*)(nodeB + (size_t)dIdx * H + cs);
            const float4* ep = (const float4*)(edge_rep + (size_t)e * H + cs);
            pS[0] = sp[0]; pS[1] = sp[1];
            pD[0] = dp[0]; pD[1] = dp[1];
            #pragma unroll
            for (int j = 0; j < 4; ++j) pE[j] = ep[j];
        }
    }

    for (; t < tEnd; ++t) {
        const int e0 = t * MB;

        // ---- stage: everything from prefetched regs (no HBM wait) ----
        {
            short* rowA = sA + row * LDA;
            if (pv) {
                #pragma unroll
                for (int j = 0; j < 2; ++j) {
                    bf16x8 lift;
                    #pragma unroll
                    for (int k = 0; k < 8; ++k)
                        lift[k] = f2bf(bf2f(pS[j][k]) + bf2f(pD[j][k]));
                    *(bf16x8*)&rowA[cs + 8 * j] = lift;
                }
                #pragma unroll
                for (int j = 0; j < 4; ++j) {
                    float4 c = pE[j];
                    s16x4 er = { f2bf(c.x), f2bf(c.y), f2bf(c.z), f2bf(c.w) };
                    *(s16x4*)&rowA[H + cs + 4 * j] = er;
                }
            } else {
                s16x4 z = {0, 0, 0, 0};
                #pragma unroll
                for (int j = 0; j < 4; ++j) {
                    int cc = cs + 4 * j;
                    *(s16x4*)&rowA[cc]     = z;
                    *(s16x4*)&rowA[H + cc] = z;
                }
            }
        }
        __syncthreads();

        // ---- issue next tile's prefetch (latency hidden under GEMM1) ----
        if (t + 1 < tEnd) {
            int e = (t + 1) * MB + row;
            pv = (e < E);
            if (pv) {
                int sIdx = eidx[e], dIdx = eidx[E + e];
                const bf16x8* sp = (const bf16x8*)(nodeB + (size_t)sIdx * H + cs);
                const bf16x8* dp = (const bf16x8*)(nodeB + (size_t)dIdx * H + cs);
                const float4* ep = (const float4*)(edge_rep + (size_t)e * H + cs);
                pS[0] = sp[0]; pS[1] = sp[1];
                pD[0] = dp[0]; pD[1] = dp[1];
                #pragma unroll
                for (int j = 0; j < 4; ++j) pE[j] = ep[j];
            }
        }

        // ---- GEMM1: acc = concat @ W1T;  acc2 = lift @ WLT (ks<4 fold) ----
        f32x4 zero = {0.f, 0.f, 0.f, 0.f};
        f32x4 acc[4], acc2[4];
        #pragma unroll
        for (int mt = 0; mt < 4; ++mt) { acc[mt] = zero; acc2[mt] = zero; }

        #pragma unroll
        for (int ks = 0; ks < 8; ++ks) {
            int k0 = ks * 32 + q * 8;
            bf16x8 aF[4];
            #pragma unroll
            for (int mt = 0; mt < 4; ++mt)
                aF[mt] = *(const bf16x8*)&sA[(mt * 16 + m) * LDA + k0];
            bf16x8 bF = *(const bf16x8*)&W1T[(wv * 16 + m) * 256 + k0];
            #pragma unroll
            for (int mt = 0; mt < 4; ++mt)
                acc[mt] = __builtin_amdgcn_mfma_f32_16x16x32_bf16(
                    aF[mt], bF, acc[mt], 0, 0, 0);
            if (ks < 4) {
                bf16x8 bL = *(const bf16x8*)&WLT[(wv * 16 + m) * 128 + k0];
                #pragma unroll
                for (int mt = 0; mt < 4; ++mt)
                    acc2[mt] = __builtin_amdgcn_mfma_f32_16x16x32_bf16(
                        aF[mt], bL, acc2[mt], 0, 0, 0);
            }
        }
        __syncthreads();   // all waves done reading sA

        // ---- epilogue: h = relu(acc) -> bf16 into the dead edge_rep half ----
        {
            int col = wv * 16 + m;
            #pragma unroll
            for (int mt = 0; mt < 4; ++mt) {
                #pragma unroll
                for (int i = 0; i < 4; ++i) {
                    int rr = (mt << 4) + (q << 2) + i;
                    float h = acc[mt][i];
                    h = h > 0.f ? h : 0.f;
                    sA[rr * LDA + H + col] = f2bf(h);
                }
            }
        }
        __syncthreads();

        // ---- coalesced hbuf dump (32B/thread from LDS) ----
        if (e0 + row < E) {
            bf16x8 h0 = *(const bf16x8*)&sA[row * LDA + H + cs];
            bf16x8 h1 = *(const bf16x8*)&sA[row * LDA + H + cs + 8];
            *(bf16x8*)&hbuf[(size_t)(e0 + row) * H + cs]     = h0;
            *(bf16x8*)&hbuf[(size_t)(e0 + row) * H + cs + 8] = h1;
        }

        // ---- GEMM2: acc3 = h @ WLT; edge_out = relu(acc2 + e2*acc3) ----
        f32x4 acc3[4];
        #pragma unroll
        for (int mt = 0; mt < 4; ++mt) acc3[mt] = zero;

        #pragma unroll
        for (int ks = 0; ks < 4; ++ks) {
            int k0 = ks * 32 + q * 8;
            bf16x8 aF[4];
            #pragma unroll
            for (int mt = 0; mt < 4; ++mt)
                aF[mt] = *(const bf16x8*)&sA[(mt * 16 + m) * LDA + H + k0];
            bf16x8 bF = *(const bf16x8*)&WLT[(wv * 16 + m) * 128 + k0];
            #pragma unroll
            for (int mt = 0; mt < 4; ++mt)
                acc3[mt] = __builtin_amdgcn_mfma_f32_16x16x32_bf16(
                    aF[mt], bF, acc3[mt], 0, 0, 0);
        }

        {
            int col = wv * 16 + m;
            #pragma unroll
            for (int mt = 0; mt < 4; ++mt) {
                #pragma unroll
                for (int i = 0; i < 4; ++i) {
                    int rr = (mt << 4) + (q << 2) + i;
                    if (e0 + rr < E) {
                        float v = acc2[mt][i] + e2 * acc3[mt][i];
                        edge_out[(size_t)(e0 + rr) * H + col] = v > 0.f ? v : 0.f;
                    }
                }
            }
        }
        __syncthreads();   // GEMM2 + dump reads done before next stage overwrites sA
    }
}

// ---------------- fused node aggregation + GEMM ----------------
// 512 threads / 8 waves per block; block owns 64 nodes. Phase 1: per round a
// wave aggregates one node: the bucket row is loaded ONCE coalesced (one int
// per lane) and edge indices are distributed by __shfl (VALU) -- no per-iter
// bucket load in the gather chain; 4 independent 16B gathers in flight/lane.
// Adds e1*node_rep, writes bf16 row into LDS. Phase 2: 64x128 GEMM with W2T.
__global__ __launch_bounds__(512) void node_fused(
    const uint4* __restrict__ hb, const int* __restrict__ bucket,
    const int* __restrict__ cnt, const float* __restrict__ node_rep,
    const short* __restrict__ W2T,
    const int* __restrict__ ovf_cnt, const int* __restrict__ ovf,
    const float* __restrict__ eps1p, float* __restrict__ node_out, int N)
{
    __shared__ short sA[MB * LDB];

    const int tid  = threadIdx.x;
    const int wv   = tid >> 6;
    const int lane = tid & 63;
    const int qt = lane >> 4, li = lane & 15;   // lane covers cols li*8..li*8+7
    const int r0 = blockIdx.x * MB;
    const float e1 = 1.f + eps1p[0];

    int m_ovf = *ovf_cnt;
    if (m_ovf > OVF_MAX) m_ovf = OVF_MAX;

    // ---- phase 1: aggregate + bias, write bf16 rows into LDS ----
    for (int rnd = 0; rnd < 8; ++rnd) {
        int n = r0 + rnd * 8 + wv;
        if (n < N) {
            int d = cnt[n];
            if (d > CAP) d = CAP;
            // coalesced bucket-row preload: lane holds slot `lane`'s edge idx
            int myIdx = (lane < d) ? bucket[n * CAP + lane] : 0;
            float a0 = 0.f, a1 = 0.f, a2 = 0.f, a3 = 0.f;
            float a4 = 0.f, a5 = 0.f, a6 = 0.f, a7 = 0.f;

            int base = 0;
            for (; base + 16 <= d; base += 16) {
                int eA = __shfl(myIdx, base + qt);
                int eB = __shfl(myIdx, base + qt + 4);
                int eC = __shfl(myIdx, base + qt + 8);
                int eD = __shfl(myIdx, base + qt + 12);
                uint4 vA = hb[(size_t)eA * 16 + li];
                uint4 vB = hb[(size_t)eB * 16 + li];
                uint4 vC = hb[(size_t)eC * 16 + li];
                uint4 vD = hb[(size_t)eD * 16 + li];
                a0 += (bflo(vA.x) + bflo(vB.x)) + (bflo(vC.x) + bflo(vD.x));
                a1 += (bfhi(vA.x) + bfhi(vB.x)) + (bfhi(vC.x) + bfhi(vD.x));
                a2 += (bflo(vA.y) + bflo(vB.y)) + (bflo(vC.y) + bflo(vD.y));
                a3 += (bfhi(vA.y) + bfhi(vB.y)) + (bfhi(vC.y) + bfhi(vD.y));
                a4 += (bflo(vA.z) + bflo(vB.z)) + (bflo(vC.z) + bflo(vD.z));
                a5 += (bfhi(vA.z) + bfhi(vB.z)) + (bfhi(vC.z) + bfhi(vD.z));
                a6 += (bflo(vA.w) + bflo(vB.w)) + (bflo(vC.w) + bflo(vD.w));
                a7 += (bfhi(vA.w) + bfhi(vB.w)) + (bfhi(vC.w) + bfhi(vD.w));
            }
            for (; base + 4 <= d; base += 4) {
                int eA = __shfl(myIdx, base + qt);
                uint4 vA = hb[(size_t)eA * 16 + li];
                a0 += bflo(vA.x);  a1 += bfhi(vA.x);
                a2 += bflo(vA.y);  a3 += bfhi(vA.y);
                a4 += bflo(vA.z);  a5 += bfhi(vA.z);
                a6 += bflo(vA.w);  a7 += bfhi(vA.w);
            }
            int rem = d - base;     // 0..3
            {
                int eA = __shfl(myIdx, base + (qt < rem ? qt : 0));
                if (qt < rem) {
                    uint4 vA = hb[(size_t)eA * 16 + li];
                    a0 += bflo(vA.x);  a1 += bfhi(vA.x);
                    a2 += bflo(vA.y);  a3 += bfhi(vA.y);
                    a4 += bflo(vA.z);  a5 += bfhi(vA.z);
                    a6 += bflo(vA.w);  a7 += bfhi(vA.w);
                }
            }
            // rare overflow entries (m_ovf ~ 0 in practice)
            for (int o = qt; o < m_ovf; o += 4) {
                if (ovf[o * 2] == n) {
                    uint4 vA = hb[(size_t)ovf[o * 2 + 1] * 16 + li];
                    a0 += bflo(vA.x);  a1 += bfhi(vA.x);
                    a2 += bflo(vA.y);  a3 += bfhi(vA.y);
                    a4 += bflo(vA.z);  a5 += bfhi(vA.z);
                    a6 += bflo(vA.w);  a7 += bfhi(vA.w);
                }
            }
            a0 += __shfl_xor(a0, 16); a1 += __shfl_xor(a1, 16);
            a2 += __shfl_xor(a2, 16); a3 += __shfl_xor(a3, 16);
            a4 += __shfl_xor(a4, 16); a5 += __shfl_xor(a5, 16);
            a6 += __shfl_xor(a6, 16); a7 += __shfl_xor(a7, 16);
            a0 += __shfl_xor(a0, 32); a1 += __shfl_xor(a1, 32);
            a2 += __shfl_xor(a2, 32); a3 += __shfl_xor(a3, 32);
            a4 += __shfl_xor(a4, 32); a5 += __shfl_xor(a5, 32);
            a6 += __shfl_xor(a6, 32); a7 += __shfl_xor(a7, 32);
            if (qt == 0) {
                const float4* np = (const float4*)(node_rep + (size_t)n * H + li * 8);
                float4 n0 = np[0], n1 = np[1];
                bf16x8 v = { f2bf(e1 * n0.x + a0), f2bf(e1 * n0.y + a1),
                             f2bf(e1 * n0.z + a2), f2bf(e1 * n0.w + a3),
                             f2bf(e1 * n1.x + a4), f2bf(e1 * n1.y + a5),
                             f2bf(e1 * n1.z + a6), f2bf(e1 * n1.w + a7) };
                *(bf16x8*)&sA[(rnd * 8 + wv) * LDB + li * 8] = v;
            }
        } else if (qt == 0) {
            bf16x8 z = {0,0,0,0,0,0,0,0};
            *(bf16x8*)&sA[(rnd * 8 + wv) * LDB + li * 8] = z;
        }
    }
    __syncthreads();

    // ---- phase 2: node_out = relu(sA @ W2T) ----
    const int m = lane & 15;
    const int q = lane >> 4;
    f32x4 zero = {0.f, 0.f, 0.f, 0.f};
    f32x4 acc[4];
    #pragma unroll
    for (int mt = 0; mt < 4; ++mt) acc[mt] = zero;

    #pragma unroll
    for (int ks = 0; ks < 4; ++ks) {
        int k0 = ks * 32 + q * 8;
        bf16x8 aF[4];
        #pragma unroll
        for (int mt = 0; mt < 4; ++mt)
            aF[mt] = *(const bf16x8*)&sA[(mt * 16 + m) * LDB + k0];
        bf16x8 bF = *(const bf16x8*)&W2T[(wv * 16 + m) * 128 + k0];
        #pragma unroll
        for (int mt = 0; mt < 4; ++mt)
            acc[mt] = __builtin_amdgcn_mfma_f32_16x16x32_bf16(
                aF[mt], bF, acc[mt], 0, 0, 0);
    }

    {
        int col = wv * 16 + m;
        #pragma unroll
        for (int mt = 0; mt < 4; ++mt) {
            #pragma unroll
            for (int i = 0; i < 4; ++i) {
                int rr = (mt << 4) + (q << 2) + i;
                if (r0 + rr < N) {
                    float v = acc[mt][i];
                    node_out[(size_t)(r0 + rr) * H + col] = v > 0.f ? v : 0.f;
                }
            }
        }
    }
}

// ---------------- node aggregation (CSR layout, middle-ws fallback) ----------
__global__ __launch_bounds__(256) void node_aggr_csr(
    const uint4* __restrict__ hb, const int* __restrict__ csr,
    const int* __restrict__ row_start, float* __restrict__ lvl, int N)
{
    const int wid = threadIdx.x >> 6, lane = threadIdx.x & 63;
    const int n = blockIdx.x * 4 + wid;
    if (n >= N) return;
    const int qt = lane >> 4, li = lane & 15;
    const int beg = row_start[n], end = row_start[n + 1];
    float a0 = 0.f, a1 = 0.f, a2 = 0.f, a3 = 0.f;
    float a4 = 0.f, a5 = 0.f, a6 = 0.f, a7 = 0.f;

    int i = beg;
    for (; i + 8 <= end; i += 8) {
        int eA = csr[i + qt], eB = csr[i + 4 + qt];
        uint4 vA = hb[(size_t)eA * 16 + li];
        uint4 vB = hb[(size_t)eB * 16 + li];
        a0 += bflo(vA.x) + bflo(vB.x);  a1 += bfhi(vA.x) + bfhi(vB.x);
        a2 += bflo(vA.y) + bflo(vB.y);  a3 += bfhi(vA.y) + bfhi(vB.y);
        a4 += bflo(vA.z) + bflo(vB.z);  a5 += bfhi(vA.z) + bfhi(vB.z);
        a6 += bflo(vA.w) + bflo(vB.w);  a7 += bfhi(vA.w) + bfhi(vB.w);
    }
    if (i + 4 <= end) {
        int eA = csr[i + qt];
        uint4 vA = hb[(size_t)eA * 16 + li];
        a0 += bflo(vA.x);  a1 += bfhi(vA.x);
        a2 += bflo(vA.y);  a3 += bfhi(vA.y);
        a4 += bflo(vA.z);  a5 += bfhi(vA.z);
        a6 += bflo(vA.w);  a7 += bfhi(vA.w);
        i += 4;
    }
    int rem = end - i;
    if (qt < rem) {
        int eA = csr[i + qt];
        uint4 vA = hb[(size_t)eA * 16 + li];
        a0 += bflo(vA.x);  a1 += bfhi(vA.x);
        a2 += bflo(vA.y);  a3 += bfhi(vA.y);
        a4 += bflo(vA.z);  a5 += bfhi(vA.z);
        a6 += bflo(vA.w);  a7 += bfhi(vA.w);
    }
    a0 += __shfl_xor(a0, 16); a1 += __shfl_xor(a1, 16);
    a2 += __shfl_xor(a2, 16); a3 += __shfl_xor(a3, 16);
    a4 += __shfl_xor(a4, 16); a5 += __shfl_xor(a5, 16);
    a6 += __shfl_xor(a6, 16); a7 += __shfl_xor(a7, 16);
    a0 += __shfl_xor(a0, 32); a1 += __shfl_xor(a1, 32);
    a2 += __shfl_xor(a2, 32); a3 += __shfl_xor(a3, 32);
    a4 += __shfl_xor(a4, 32); a5 += __shfl_xor(a5, 32);
    a6 += __shfl_xor(a6, 32); a7 += __shfl_xor(a7, 32);
    if (qt == 0) {
        float* dst = lvl + (size_t)n * H + li * 8;
        float4 o0; o0.x = a0; o0.y = a1; o0.z = a2; o0.w = a3;
        float4 o1; o1.x = a4; o1.y = a5; o1.z = a6; o1.w = a7;
        *(float4*)dst = o0;
        *(float4*)(dst + 4) = o1;
    }
}

// ---------------- LEGACY edge kernel (atomic scatter) -- tiny-ws fallback ----
__global__ __launch_bounds__(256) void edge_kernel(
    const float* __restrict__ node_rep, const float* __restrict__ edge_rep,
    const int* __restrict__ eidx,
    const short* __restrict__ W1T, const short* __restrict__ WLT,
    const float* __restrict__ eps2p,
    float* __restrict__ lvl, float* __restrict__ edge_out, int E)
{
    __shared__ short sA[MB * LDA];
    __shared__ short sB[MB * LDB];
    __shared__ int sSrc[MB], sDst[MB];

    const int tid = threadIdx.x;
    const int e0  = blockIdx.x * MB;
    const float e2 = 1.f + eps2p[0];
    {
        int row  = tid >> 2;
        int cseg = (tid & 3) << 5;
        int e = e0 + row;
        int sIdx = 0, dIdx = 0;
        bool ev = (e < E);
        if (ev) { sIdx = eidx[e]; dIdx = eidx[E + e]; }
        if ((tid & 3) == 0) { sSrc[row] = sIdx; sDst[row] = dIdx; }
        short* rowA = sA + row * LDA;
        if (ev) {
            const float4* sp = (const float4*)(node_rep + (size_t)sIdx * H + cseg);
            const float4* dp = (const float4*)(node_rep + (size_t)dIdx * H + cseg);
            const float4* ep = (const float4*)(edge_rep + (size_t)e * H + cseg);
            #pragma unroll
            for (int j = 0; j < 8; ++j) {
                float4 a = sp[j], b = dp[j], c = ep[j];
                int cc = cseg + 4 * j;
                s16x4 lift = { f2bf(a.x + b.x), f2bf(a.y + b.y),
                               f2bf(a.z + b.z), f2bf(a.w + b.w) };
                s16x4 er   = { f2bf(c.x), f2bf(c.y), f2bf(c.z), f2bf(c.w) };
                *(s16x4*)&rowA[cc]      = lift;
                *(s16x4*)&rowA[H + cc]  = er;
            }
        } else {
            s16x4 z = {0, 0, 0, 0};
            #pragma unroll
            for (int j = 0; j < 8; ++j) {
                int cc = cseg + 4 * j;
                *(s16x4*)&rowA[cc]     = z;
                *(s16x4*)&rowA[H + cc] = z;
            }
        }
    }
    __syncthreads();

    const int wave = tid >> 6;
    const int lane = tid & 63;
    const int m = lane & 15;
    const int q = lane >> 4;

    f32x4 zero = {0.f, 0.f, 0.f, 0.f};
    f32x4 acc[4][2];
    #pragma unroll
    for (int mt = 0; mt < 4; ++mt)
        #pragma unroll
        for (int nt = 0; nt < 2; ++nt) acc[mt][nt] = zero;

    #pragma unroll
    for (int ks = 0; ks < 8; ++ks) {
        int k0 = ks * 32 + q * 8;
        bf16x8 aF[4];
        #pragma unroll
        for (int mt = 0; mt < 4; ++mt)
            aF[mt] = *(const bf16x8*)&sA[(mt * 16 + m) * LDA + k0];
        bf16x8 bF[2];
        #pragma unroll
        for (int nt = 0; nt < 2; ++nt) {
            int n = (wave << 5) + (nt << 4) + m;
            bF[nt] = *(const bf16x8*)&W1T[n * 256 + k0];
        }
        #pragma unroll
        for (int mt = 0; mt < 4; ++mt)
            #pragma unroll
            for (int nt = 0; nt < 2; ++nt)
                acc[mt][nt] = __builtin_amdgcn_mfma_f32_16x16x32_bf16(
                    aF[mt], bF[nt], acc[mt][nt], 0, 0, 0);
    }

    #pragma unroll
    for (int mt = 0; mt < 4; ++mt) {
        #pragma unroll
        for (int nt = 0; nt < 2; ++nt) {
            int col = (wave << 5) + (nt << 4) + m;
            #pragma unroll
            for (int i = 0; i < 4; ++i) {
                int rr = (mt << 4) + (q << 2) + i;
                if (e0 + rr < E) {
                    float h = acc[mt][nt][i];
                    h = h > 0.f ? h : 0.f;
                    int sn = sSrc[rr], dn = sDst[rr];
                    atomicAdd(lvl + (size_t)sn * H + col, h);
                    atomicAdd(lvl + (size_t)dn * H + col, h);
                    float b2 = e2 * h + bf2f(sA[rr * LDA + col]);
                    sB[rr * LDB + col] = f2bf(b2);
                }
            }
        }
    }
    __syncthreads();

    f32x4 acc2[4][2];
    #pragma unroll
    for (int mt = 0; mt < 4; ++mt)
        #pragma unroll
        for (int nt = 0; nt < 2; ++nt) acc2[mt][nt] = zero;

    #pragma unroll
    for (int ks = 0; ks < 4; ++ks) {
        int k0 = ks * 32 + q * 8;
        bf16x8 aF[4];
        #pragma unroll
        for (int mt = 0; mt < 4; ++mt)
            aF[mt] = *(const bf16x8*)&sB[(mt * 16 + m) * LDB + k0];
        bf16x8 bF[2];
        #pragma unroll
        for (int nt = 0; nt < 2; ++nt) {
            int n = (wave << 5) + (nt << 4) + m;
            bF[nt] = *(const bf16x8*)&WLT[n * 128 + k0];
        }
        #pragma unroll
        for (int mt = 0; mt < 4; ++mt)
            #pragma unroll
            for (int nt = 0; nt < 2; ++nt)
                acc2[mt][nt] = __builtin_amdgcn_mfma_f32_16x16x32_bf16(
                    aF[mt], bF[nt], acc2[mt][nt], 0, 0, 0);
    }

    #pragma unroll
    for (int mt = 0; mt < 4; ++mt) {
        #pragma unroll
        for (int nt = 0; nt < 2; ++nt) {
            int col = (wave << 5) + (nt << 4) + m;
            #pragma unroll
            for (int i = 0; i < 4; ++i) {
                int rr = (mt << 4) + (q << 2) + i;
                if (e0 + rr < E) {
                    float v = acc2[mt][nt][i];
                    edge_out[(size_t)(e0 + rr) * H + col] = v > 0.f ? v : 0.f;
                }
            }
        }
    }
}

// ---------------- node kernel (fallback paths) ----------------
__global__ __launch_bounds__(256) void node_kernel(
    const float* __restrict__ node_rep, const float* __restrict__ lvl,
    const short* __restrict__ W2T, const float* __restrict__ eps1p,
    float* __restrict__ node_out, int N)
{
    __shared__ short sA[MB * LDB];

    const int tid = threadIdx.x;
    const int r0  = blockIdx.x * MB;
    const float e1 = 1.f + eps1p[0];

    {
        int row  = tid >> 2;
        int cseg = (tid & 3) << 5;
        int r = r0 + row;
        short* rowA = sA + row * LDB;
        if (r < N) {
            const float4* np = (const float4*)(node_rep + (size_t)r * H + cseg);
            const float4* lp = (const float4*)(lvl + (size_t)r * H + cseg);
            #pragma unroll
            for (int j = 0; j < 8; ++j) {
                float4 a = np[j], b = lp[j];
                int cc = cseg + 4 * j;
                s16x4 v = { f2bf(e1 * a.x + b.x), f2bf(e1 * a.y + b.y),
                            f2bf(e1 * a.z + b.z), f2bf(e1 * a.w + b.w) };
                *(s16x4*)&rowA[cc] = v;
            }
        } else {
            s16x4 z = {0, 0, 0, 0};
            #pragma unroll
            for (int j = 0; j < 8; ++j) *(s16x4*)&rowA[cseg + 4 * j] = z;
        }
    }
    __syncthreads();

    const int wave = tid >> 6;
    const int lane = tid & 63;
    const int m = lane & 15;
    const int q = lane >> 4;

    f32x4 zero = {0.f, 0.f, 0.f, 0.f};
    f32x4 acc[4][2];
    #pragma unroll
    for (int mt = 0; mt < 4; ++mt)
        #pragma unroll
        for (int nt = 0; nt < 2; ++nt) acc[mt][nt] = zero;

    #pragma unroll
    for (int ks = 0; ks < 4; ++ks) {
        int k0 = ks * 32 + q * 8;
        bf16x8 aF[4];
        #pragma unroll
        for (int mt = 0; mt < 4; ++mt)
            aF[mt] = *(const bf16x8*)&sA[(mt * 16 + m) * LDB + k0];
        bf16x8 bF[2];
        #pragma unroll
        for (int nt = 0; nt < 2; ++nt) {
            int n = (wave << 5) + (nt << 4) + m;
            bF[nt] = *(const bf16x8*)&W2T[n * 128 + k0];
        }
        #pragma unroll
        for (int mt = 0; mt < 4; ++mt)
            #pragma unroll
            for (int nt = 0; nt < 2; ++nt)
                acc[mt][nt] = __builtin_amdgcn_mfma_f32_16x16x32_bf16(
                    aF[mt], bF[nt], acc[mt][nt], 0, 0, 0);
    }

    #pragma unroll
    for (int mt = 0; mt < 4; ++mt) {
        #pragma unroll
        for (int nt = 0; nt < 2; ++nt) {
            int col = (wave << 5) + (nt << 4) + m;
            #pragma unroll
            for (int i = 0; i < 4; ++i) {
                int rr = (mt << 4) + (q << 2) + i;
                if (r0 + rr < N) {
                    float v = acc[mt][nt][i];
                    node_out[(size_t)(r0 + rr) * H + col] = v > 0.f ? v : 0.f;
                }
            }
        }
    }
}

static inline size_t algn(size_t x) { return (x + 255) & ~(size_t)255; }

extern "C" void kernel_launch(void* const* d_in, const int* in_sizes, int n_in,
                              void* d_out, int out_size, void* d_ws, size_t ws_size,
                              hipStream_t stream) {
    const float* node_rep = (const float*)d_in[0];
    const float* edge_rep = (const float*)d_in[1];
    const int*   eidx     = (const int*)d_in[2];
    const float* W1       = (const float*)d_in[3];
    const float* W2       = (const float*)d_in[4];
    const float* WL       = (const float*)d_in[5];
    const float* eps1     = (const float*)d_in[6];
    const float* eps2     = (const float*)d_in[7];

    const int N = in_sizes[0] / H;     // 50000
    const int E = in_sizes[1] / H;     // 800000

    float* node_out = (float*)d_out;
    float* edge_out = (float*)d_out + (size_t)N * H;
    float* lvl = node_out;             // fallback paths only (in-place safe)

    char* ws = (char*)d_ws;
    short* W1T = (short*)ws;                       // 64 KB
    short* W2T = (short*)(ws + 65536);             // 32 KB
    short* WLT = (short*)(ws + 65536 + 32768);     // 32 KB
    size_t off0 = 131072;

    // shared buffers (both fast paths)
    short* hbuf  = (short*)(ws + off0);
    size_t offh  = off0 + algn((size_t)E * H * sizeof(short));
    short* nodeB = (short*)(ws + offh);
    size_t offn  = offh + algn((size_t)N * H * sizeof(short));

    // bucket-path region
    size_t ob = offn;
    int* cnt     = (int*)(ws + ob); ob += algn((size_t)N * 4);
    int* ovf_cnt = (int*)(ws + ob); ob += 256;
    int* ovf     = (int*)(ws + ob); ob += algn((size_t)OVF_MAX * 2 * 4);
    int* bucket  = (int*)(ws + ob); ob += algn((size_t)N * CAP * 4);
    const size_t need_bucket = ob;

    // csr-path region (overlaps bucket region; only one path runs)
    size_t oc = offn;
    int* deg       = (int*)(ws + oc); oc += algn((size_t)N * 4);
    int* row_start = (int*)(ws + oc); oc += algn((size_t)(N + 1) * 4);
    int* cursor    = (int*)(ws + oc); oc += algn((size_t)N * 4);
    int* csr       = (int*)(ws + oc); oc += algn((size_t)2 * E * 4);
    const size_t need_csr = oc;

    const int twoE = 2 * E;
    const int egrid = (E + MB - 1) / MB;
    const int ngrid = (N + MB - 1) / MB;
    const int total8 = (N * H) / 8;
    const int nTiles = (E + MB - 1) / MB;
    const int pgrid = (nTiles + TPB - 1) / TPB;

    if (ws_size >= need_bucket) {
        prep_all<<<(total8 + 255) / 256, 256, 0, stream>>>(
            W1, W2, WL, node_rep, W1T, W2T, WLT, nodeB, total8);
        hipMemsetAsync(cnt, 0, (size_t)N * 4, stream);
        hipMemsetAsync(ovf_cnt, 0, 4, stream);
        // edge tiles + concurrent bucket-builder blocks in ONE launch
        edge_pipe<<<pgrid + BKG, 512, 0, stream>>>(
            nodeB, edge_rep, eidx, W1T, WLT, eps2, hbuf, edge_out,
            cnt, bucket, ovf_cnt, ovf, E, nTiles, pgrid);
        node_fused<<<(N + MB - 1) / MB, 512, 0, stream>>>(
            (const uint4*)hbuf, bucket, cnt, node_rep, W2T,
            ovf_cnt, ovf, eps1, node_out, N);
    } else if (ws_size >= need_csr) {
        prep_all<<<(total8 + 255) / 256, 256, 0, stream>>>(
            W1, W2, WL, node_rep, W1T, W2T, WLT, nodeB, total8);
        hipMemsetAsync(deg, 0, (size_t)N * 4, stream);
        count_deg<<<(twoE + 255) / 256, 256, 0, stream>>>(eidx, deg, twoE);
        scan_deg<<<1, 1024, 0, stream>>>(deg, row_start, cursor, N);
        fill_csr<<<(twoE + 255) / 256, 256, 0, stream>>>(eidx, cursor, csr, E);
        edge_pipe<<<pgrid, 512, 0, stream>>>(
            nodeB, edge_rep, eidx, W1T, WLT, eps2, hbuf, edge_out,
            nullptr, nullptr, nullptr, nullptr, E, nTiles, pgrid);
        node_aggr_csr<<<(N + 3) / 4, 256, 0, stream>>>(
            (const uint4*)hbuf, csr, row_start, lvl, N);
        node_kernel<<<ngrid, 256, 0, stream>>>(
            node_rep, lvl, W2T, eps1, node_out, N);
    } else {
        // LEGACY: atomic scatter (weights only need 128 KB)
        prep_all<<<(total8 + 255) / 256, 256, 0, stream>>>(
            W1, W2, WL, node_rep, W1T, W2T, WLT, (short*)W1T, 0);
        hipMemsetAsync(lvl, 0, (size_t)N * H * sizeof(float), stream);
        edge_kernel<<<egrid, 256, 0, stream>>>(
            node_rep, edge_rep, eidx, W1T, WLT, eps2, lvl, edge_out, E);
        node_kernel<<<ngrid, 256, 0, stream>>>(
            node_rep, lvl, W2T, eps1, node_out, N);
    }
}